// Round 5
// baseline (754.832 us; speedup 1.0000x reference)
//
#include <hip/hip_runtime.h>
#include <hip/hip_fp16.h>

// ---------------------------------------------------------------------------
// MaskedGNN: 6-layer GCN, weight-free scaled-hidden formulation.
//  Store H' = dis * h  (fp16). Then per layer:
//    z_i = dis_i * ( sum_{src in N(i)} H'_src  +  H'_i )      [pure gather-sum]
//    h_next' = dis * relu(z @ W + b)
//  Encoder: x' = dis*x (f32x4, L2-resident); zx_i = dis_i*(sum x'_src + x'_i).
//  Decoder: t' = H' . W_dec ; out_i = (dis_i*(sum t'_src + t'_i) + b) * mask.
//  CSR stores ONLY src index (4B/edge). GEMM: MFMA f32_16x16x32_f16 with W
//  split hi/lo fp16 (W exact), fp32 accum, in-place.
// ---------------------------------------------------------------------------

#define HW 128  // hidden width

typedef _Float16 f16x8 __attribute__((ext_vector_type(8)));
typedef float f32x4 __attribute__((ext_vector_type(4)));

// ---------------- CSR build ----------------
__global__ void k_zero_i32(int* __restrict__ a, int n) {
    int i = blockIdx.x * 256 + threadIdx.x;
    if (i < n) a[i] = 0;
}

__global__ void k_hist(const int* __restrict__ dstA, int* __restrict__ deg, int e) {
    int i = blockIdx.x * 256 + threadIdx.x;
    if (i < e) atomicAdd(&deg[dstA[i]], 1);
}

// scan_a also produces dis = rsqrt(1+deg)
__global__ void k_scan_a(const int* __restrict__ deg, int* __restrict__ tmp,
                         int* __restrict__ bsum, float* __restrict__ dis, int n) {
    __shared__ int s[256];
    int t = threadIdx.x;
    int i = blockIdx.x * 256 + t;
    int d0 = (i < n) ? deg[i] : 0;
    s[t] = d0;
    __syncthreads();
    for (int off = 1; off < 256; off <<= 1) {
        int v = (t >= off) ? s[t - off] : 0;
        __syncthreads();
        s[t] += v;
        __syncthreads();
    }
    if (i < n) {
        tmp[i] = s[t];
        dis[i] = rsqrtf(1.0f + (float)d0);
    }
    if (t == 255) bsum[blockIdx.x] = s[255];
}

__global__ void k_scan_b(int* __restrict__ bsum, int nb) {
    __shared__ int s[512];
    int t = threadIdx.x;
    s[t] = (t < nb) ? bsum[t] : 0;
    __syncthreads();
    for (int off = 1; off < 512; off <<= 1) {
        int v = (t >= off) ? s[t - off] : 0;
        __syncthreads();
        s[t] += v;
        __syncthreads();
    }
    if (t < nb) bsum[t] = s[t];
}

__global__ void k_scan_c(const int* __restrict__ tmp, const int* __restrict__ deg,
                         const int* __restrict__ bsum, int* __restrict__ row_start,
                         int* __restrict__ cursor, int n, int etot) {
    int i = blockIdx.x * 256 + threadIdx.x;
    if (i < n) {
        int off = blockIdx.x ? bsum[blockIdx.x - 1] : 0;
        row_start[i] = tmp[i] - deg[i] + off;  // exclusive scan
        cursor[i] = 0;
    }
    if (i == 0) row_start[n] = etot;
}

// csr[j] = src only (4B). Nontemporal store: no RFO, less L2 pollution.
__global__ void k_scatter(const int* __restrict__ srcA, const int* __restrict__ dstA,
                          const int* __restrict__ row_start, int* __restrict__ cursor,
                          int* __restrict__ csr, int e) {
    int i = blockIdx.x * 256 + threadIdx.x;
    if (i >= e) return;
    int d = dstA[i];
    int s = srcA[i];
    int p = atomicAdd(&cursor[d], 1);
    __builtin_nontemporal_store(s, &csr[row_start[d] + p]);
}

// ---------------- input prescale: x4[i] = dis_i * x_i (padded to float4) ----
__global__ void k_prep_x(const float* __restrict__ x, const float* __restrict__ dis,
                         float4* __restrict__ x4, int n) {
    int i = blockIdx.x * 256 + threadIdx.x;
    if (i >= n) return;
    float d = dis[i];
    x4[i] = make_float4(x[i * 3 + 0] * d, x[i * 3 + 1] * d, x[i * 3 + 2] * d, 0.f);
}

// ---------------- W prep: transpose + hi/lo fp16 split ----------------
__global__ void k_prep_wt(const float* __restrict__ Wp, __half* __restrict__ WTh,
                          __half* __restrict__ WTl, int total) {
    int t = blockIdx.x * 256 + threadIdx.x;
    if (t >= total) return;
    int l = t >> 14;
    int kc = t & 16383;
    int k = kc >> 7, c = kc & 127;
    float w = Wp[t];
    __half hi = __float2half_rn(w);
    __half lo = __float2half_rn(w - __half2float(hi));
    size_t o = ((size_t)l << 14) + (size_t)c * HW + k;
    WTh[o] = hi;
    WTl[o] = lo;
}

// ---------------- encoder ----------------
// zx[i] = dis_i * ( sum_src x4[src] + x4[i] )
__global__ void k_enc_agg(const float4* __restrict__ x4, const int* __restrict__ rs,
                          const int* __restrict__ csr, const float* __restrict__ dis,
                          float4* __restrict__ zx, int n) {
    int i = blockIdx.x * 256 + threadIdx.x;
    if (i >= n) return;
    float4 a = x4[i];
    int e1 = rs[i + 1];
    for (int j = rs[i]; j < e1; ++j) {
        float4 v = x4[csr[j]];
        a.x += v.x; a.y += v.y; a.z += v.z;
    }
    float d = dis[i];
    zx[i] = make_float4(a.x * d, a.y * d, a.z * d, 0.f);
}

// H'[i][c] = dis_i * relu( zx[i] . We[:,c] + be[c] )
__global__ void k_enc_gemm(const float4* __restrict__ zx, const float* __restrict__ We,
                           const float* __restrict__ be, const float* __restrict__ dis,
                           __half* __restrict__ H, int n) {
    int t = blockIdx.x * 256 + threadIdx.x;
    int i = t >> 7;
    int c = t & 127;
    if (i >= n) return;
    float4 z = zx[i];
    float v = z.x * We[c] + z.y * We[HW + c] + z.z * We[2 * HW + c] + be[c];
    H[(size_t)i * HW + c] = __float2half_rn(fmaxf(v, 0.f) * dis[i]);
}

// ---------------- width-128 aggregate: one wave per node, weight-free -------
// Z[i] = fp16( dis_i * ( H'[i] + sum_src H'[src] ) )
__global__ __launch_bounds__(256) void k_agg128(const __half2* __restrict__ Hin,
                                                const int* __restrict__ rs,
                                                const int* __restrict__ csr,
                                                const float* __restrict__ dis,
                                                __half2* __restrict__ Z, int n) {
    int node = blockIdx.x * 4 + (threadIdx.x >> 6);
    int lane = threadIdx.x & 63;
    if (node >= n) return;
    float2 a0 = __half22float2(Hin[(size_t)node * 64 + lane]);  // self term
    float2 a1 = make_float2(0.f, 0.f), a2 = a1, a3 = a1;
    float2 a4 = a1, a5 = a1, a6 = a1, a7 = a1;
    int e0 = rs[node], e1 = rs[node + 1];
    for (int base = e0; base < e1; base += 64) {
        int cnt = e1 - base;
        if (cnt > 64) cnt = 64;
        int myj = base + lane;
        int sl = (myj < e1) ? csr[myj] : 0;
        int k = 0;
        for (; k + 8 <= cnt; k += 8) {
            int s0 = __shfl(sl, k + 0), s1 = __shfl(sl, k + 1);
            int s2 = __shfl(sl, k + 2), s3 = __shfl(sl, k + 3);
            int s4 = __shfl(sl, k + 4), s5 = __shfl(sl, k + 5);
            int s6 = __shfl(sl, k + 6), s7 = __shfl(sl, k + 7);
            __half2 g0 = Hin[(size_t)s0 * 64 + lane];
            __half2 g1 = Hin[(size_t)s1 * 64 + lane];
            __half2 g2 = Hin[(size_t)s2 * 64 + lane];
            __half2 g3 = Hin[(size_t)s3 * 64 + lane];
            __half2 g4 = Hin[(size_t)s4 * 64 + lane];
            __half2 g5 = Hin[(size_t)s5 * 64 + lane];
            __half2 g6 = Hin[(size_t)s6 * 64 + lane];
            __half2 g7 = Hin[(size_t)s7 * 64 + lane];
            float2 v0 = __half22float2(g0), v1 = __half22float2(g1);
            float2 v2 = __half22float2(g2), v3 = __half22float2(g3);
            float2 v4 = __half22float2(g4), v5 = __half22float2(g5);
            float2 v6 = __half22float2(g6), v7 = __half22float2(g7);
            a0.x += v0.x; a0.y += v0.y;
            a1.x += v1.x; a1.y += v1.y;
            a2.x += v2.x; a2.y += v2.y;
            a3.x += v3.x; a3.y += v3.y;
            a4.x += v4.x; a4.y += v4.y;
            a5.x += v5.x; a5.y += v5.y;
            a6.x += v6.x; a6.y += v6.y;
            a7.x += v7.x; a7.y += v7.y;
        }
        for (; k < cnt; ++k) {
            int s = __shfl(sl, k);
            float2 v = __half22float2(Hin[(size_t)s * 64 + lane]);
            a0.x += v.x; a0.y += v.y;
        }
    }
    float d = dis[node];
    float2 acc;
    acc.x = d * (((a0.x + a1.x) + (a2.x + a3.x)) + ((a4.x + a5.x) + (a6.x + a7.x)));
    acc.y = d * (((a0.y + a1.y) + (a2.y + a3.y)) + ((a4.y + a5.y) + (a6.y + a7.y)));
    Z[(size_t)node * 64 + lane] = __floats2half2_rn(acc.x, acc.y);
}

// ---------------- MFMA GEMM: H' = dis * relu(Z @ W + b), in place -----------
// 256 threads = 4 waves; block owns 256 rows, wave owns 64 rows x 128 cols.
// Layout (16x16x32): A row=lane&15, k=(lane>>4)*8+j ; B col=lane&15, same k;
// C/D col=lane&15, row=(lane>>4)*4+reg.
#define GBM 256
__global__ __launch_bounds__(256) void k_gemm_mfma(const __half* __restrict__ Z,
                                                   const __half* __restrict__ WTh,
                                                   const __half* __restrict__ WTl,
                                                   const float* __restrict__ b,
                                                   const float* __restrict__ dis,
                                                   __half* __restrict__ Hout, int n) {
    int wave = threadIdx.x >> 6, lane = threadIdx.x & 63;
    int q = lane >> 4, r16 = lane & 15;
    int row0 = blockIdx.x * GBM + wave * 64;

    f32x4 acc[4][8];
#pragma unroll
    for (int mt = 0; mt < 4; ++mt)
#pragma unroll
        for (int nt = 0; nt < 8; ++nt) acc[mt][nt] = (f32x4)0.f;

#pragma unroll
    for (int ks = 0; ks < 4; ++ks) {
        f16x8 afr[4];
#pragma unroll
        for (int mt = 0; mt < 4; ++mt) {
            int row = row0 + mt * 16 + r16;
            row = row < n ? row : (n - 1);  // clamp; results discarded at store
            afr[mt] = *(const f16x8*)(Z + (size_t)row * HW + ks * 32 + q * 8);
        }
#pragma unroll
        for (int nt = 0; nt < 8; ++nt) {
            f16x8 bh = *(const f16x8*)(WTh + (size_t)(nt * 16 + r16) * HW + ks * 32 + q * 8);
            f16x8 bl = *(const f16x8*)(WTl + (size_t)(nt * 16 + r16) * HW + ks * 32 + q * 8);
#pragma unroll
            for (int mt = 0; mt < 4; ++mt) {
                acc[mt][nt] = __builtin_amdgcn_mfma_f32_16x16x32_f16(afr[mt], bh, acc[mt][nt], 0, 0, 0);
                acc[mt][nt] = __builtin_amdgcn_mfma_f32_16x16x32_f16(afr[mt], bl, acc[mt][nt], 0, 0, 0);
            }
        }
    }

    float dr[4][4];
#pragma unroll
    for (int mt = 0; mt < 4; ++mt)
#pragma unroll
        for (int r = 0; r < 4; ++r) {
            int row = row0 + mt * 16 + q * 4 + r;
            dr[mt][r] = (row < n) ? dis[row] : 0.f;
        }

#pragma unroll
    for (int nt = 0; nt < 8; ++nt) {
        float bias = b[nt * 16 + r16];
#pragma unroll
        for (int mt = 0; mt < 4; ++mt) {
#pragma unroll
            for (int r = 0; r < 4; ++r) {
                int row = row0 + mt * 16 + q * 4 + r;
                if (row < n) {
                    float v = fmaxf(acc[mt][nt][r] + bias, 0.f) * dr[mt][r];
                    Hout[(size_t)row * HW + nt * 16 + r16] = __float2half_rn(v);
                }
            }
        }
    }
}

// ---------------- decoder ----------------
// t'[i] = H'[i] . Wd
__global__ __launch_bounds__(256) void k_dec_mv(const __half2* __restrict__ H,
                                                const float* __restrict__ Wd,
                                                float* __restrict__ t, int n) {
    int node = blockIdx.x * 4 + (threadIdx.x >> 6);
    int lane = threadIdx.x & 63;
    if (node >= n) return;
    float2 h = __half22float2(H[(size_t)node * 64 + lane]);
    float2 w = ((const float2*)Wd)[lane];
    float s = h.x * w.x + h.y * w.y;
    for (int off = 32; off; off >>= 1) s += __shfl_down(s, off);
    if (lane == 0) t[node] = s;
}

// out[i] = (dis_i * (sum_src t'[src] + t'[i]) + b) * mask[i]
__global__ void k_dec_out(const float* __restrict__ t, const int* __restrict__ rs,
                          const int* __restrict__ csr, const float* __restrict__ dis,
                          const float* __restrict__ bdec, const float* __restrict__ mask,
                          float* __restrict__ out, int n) {
    int i = blockIdx.x * 256 + threadIdx.x;
    if (i >= n) return;
    float acc = t[i];
    int e1 = rs[i + 1];
    for (int j = rs[i]; j < e1; ++j) acc += t[csr[j]];
    out[i] = (dis[i] * acc + bdec[0]) * mask[i];
}

// ---------------------------------------------------------------------------
static inline size_t align256(size_t x) { return (x + 255) & ~(size_t)255; }

extern "C" void kernel_launch(void* const* d_in, const int* in_sizes, int n_in,
                              void* d_out, int out_size, void* d_ws, size_t ws_size,
                              hipStream_t stream) {
    const float* x     = (const float*)d_in[0];
    const float* mask  = (const float*)d_in[1];
    const int*   ei    = (const int*)d_in[2];
    const float* W_enc = (const float*)d_in[3];
    const float* b_enc = (const float*)d_in[4];
    const float* W_p   = (const float*)d_in[5];
    const float* b_p   = (const float*)d_in[6];
    const float* W_dec = (const float*)d_in[7];
    const float* b_dec = (const float*)d_in[8];

    const int N = in_sizes[1];
    const int E = in_sizes[2] / 2;
    const int* srcA = ei;
    const int* dstA = ei + E;

    char* p = (char*)d_ws;
    size_t off = 0;
    auto carve = [&](size_t bytes) {
        void* r = p + off;
        off += align256(bytes);
        return r;
    };
    int*    deg       = (int*)carve((size_t)N * 4);
    int*    cursor    = (int*)carve((size_t)N * 4);
    int*    row_start = (int*)carve((size_t)(N + 1) * 4);
    int*    bsum      = (int*)carve(512 * 4);
    int*    csr       = (int*)carve((size_t)E * 4);
    float*  dis       = (float*)carve((size_t)N * 4);
    float4* x4        = (float4*)carve((size_t)N * 16);
    float4* zx        = (float4*)carve((size_t)N * 16);  // also scan tmp
    float*  tdec      = (float*)carve((size_t)N * 4);
    __half* WTh       = (__half*)carve((size_t)4 * HW * HW * 2);
    __half* WTl       = (__half*)carve((size_t)4 * HW * HW * 2);
    __half* HA        = (__half*)carve((size_t)N * HW * 2);
    __half* HB        = (__half*)carve((size_t)N * HW * 2);
    int*    tmp       = (int*)zx;

    const int gN   = (N + 255) / 256;
    const int gE   = (E + 255) / 256;
    const int gNd4 = (N + 3) / 4;
    const int gG   = (N + GBM - 1) / GBM;
    const int WPT  = 4 * HW * HW;

    // ---- CSR build + preps ----
    k_zero_i32<<<gN, 256, 0, stream>>>(deg, N);
    k_hist<<<gE, 256, 0, stream>>>(dstA, deg, E);
    k_scan_a<<<gN, 256, 0, stream>>>(deg, tmp, bsum, dis, N);
    k_scan_b<<<1, 512, 0, stream>>>(bsum, gN);
    k_scan_c<<<gN, 256, 0, stream>>>(tmp, deg, bsum, row_start, cursor, N, E);
    k_scatter<<<gE, 256, 0, stream>>>(srcA, dstA, row_start, cursor, csr, E);
    k_prep_x<<<gN, 256, 0, stream>>>(x, dis, x4, N);
    k_prep_wt<<<(WPT + 255) / 256, 256, 0, stream>>>(W_p, WTh, WTl, WPT);

    // ---- encoder ----
    k_enc_agg<<<gN, 256, 0, stream>>>(x4, row_start, csr, dis, zx, N);
    k_enc_gemm<<<(N * HW + 255) / 256, 256, 0, stream>>>(zx, W_enc, b_enc, dis, HA, N);

    // ---- 4 processor layers: agg(Hin->Hoth), gemm in place on Hoth ----
    __half* Hin = HA;
    __half* Hoth = HB;
    for (int l = 0; l < 4; ++l) {
        k_agg128<<<gNd4, 256, 0, stream>>>((const __half2*)Hin, row_start, csr, dis,
                                           (__half2*)Hoth, N);
        k_gemm_mfma<<<gG, 256, 0, stream>>>(Hoth, WTh + (size_t)l * HW * HW,
                                            WTl + (size_t)l * HW * HW,
                                            b_p + (size_t)l * HW, dis, Hoth, N);
        __half* t = Hin; Hin = Hoth; Hoth = t;
    }

    // ---- decoder ----
    k_dec_mv<<<gNd4, 256, 0, stream>>>((const __half2*)Hin, W_dec, tdec, N);
    k_dec_out<<<gN, 256, 0, stream>>>(tdec, row_start, csr, dis, b_dec, mask,
                                      (float*)d_out, N);
}

// Round 6
// 645.319 us; speedup vs baseline: 1.1697x; 1.1697x over previous
//
#include <hip/hip_runtime.h>
#include <hip/hip_fp16.h>

// ---------------------------------------------------------------------------
// MaskedGNN: 6-layer GCN, weight-free scaled-hidden formulation.
//  Store H' = dis * h  (fp16). Per layer:
//    z_i = dis_i * ( sum_{src in N(i)} H'_src + H'_i )   [pure gather-sum]
//    h_next' = dis * relu(z @ W + b)
//  CSR stores ONLY src index (4B/edge). GEMM: MFMA f32_16x16x32_f16, W split
//  hi/lo fp16 (W exact), fp32 accum, in-place. Last GEMM fuses decoder matvec.
//  Aggregation: wave = 4 nodes x 16 lanes, 16B/lane loads (1KB/instr),
//  depth-4 unroll -> 16 rows (4KB) in flight per wave.
// ---------------------------------------------------------------------------

#define HW 128  // hidden width

typedef _Float16 f16x8 __attribute__((ext_vector_type(8)));
typedef float f32x4 __attribute__((ext_vector_type(4)));

// ---------------- CSR build ----------------
__global__ void k_zero_i32(int* __restrict__ a, int n) {
    int i = blockIdx.x * 256 + threadIdx.x;
    if (i < n) a[i] = 0;
}

__global__ void k_hist(const int* __restrict__ dstA, int* __restrict__ deg, int e) {
    int i = blockIdx.x * 256 + threadIdx.x;
    if (i < e) atomicAdd(&deg[dstA[i]], 1);
}

// scan_a also produces dis = rsqrt(1+deg)
__global__ void k_scan_a(const int* __restrict__ deg, int* __restrict__ tmp,
                         int* __restrict__ bsum, float* __restrict__ dis, int n) {
    __shared__ int s[256];
    int t = threadIdx.x;
    int i = blockIdx.x * 256 + t;
    int d0 = (i < n) ? deg[i] : 0;
    s[t] = d0;
    __syncthreads();
    for (int off = 1; off < 256; off <<= 1) {
        int v = (t >= off) ? s[t - off] : 0;
        __syncthreads();
        s[t] += v;
        __syncthreads();
    }
    if (i < n) {
        tmp[i] = s[t];
        dis[i] = rsqrtf(1.0f + (float)d0);
    }
    if (t == 255) bsum[blockIdx.x] = s[255];
}

__global__ void k_scan_b(int* __restrict__ bsum, int nb) {
    __shared__ int s[512];
    int t = threadIdx.x;
    s[t] = (t < nb) ? bsum[t] : 0;
    __syncthreads();
    for (int off = 1; off < 512; off <<= 1) {
        int v = (t >= off) ? s[t - off] : 0;
        __syncthreads();
        s[t] += v;
        __syncthreads();
    }
    if (t < nb) bsum[t] = s[t];
}

__global__ void k_scan_c(const int* __restrict__ tmp, const int* __restrict__ deg,
                         const int* __restrict__ bsum, int* __restrict__ row_start,
                         int* __restrict__ cursor, int n, int etot) {
    int i = blockIdx.x * 256 + threadIdx.x;
    if (i < n) {
        int off = blockIdx.x ? bsum[blockIdx.x - 1] : 0;
        row_start[i] = tmp[i] - deg[i] + off;  // exclusive scan
        cursor[i] = 0;
    }
    if (i == 0) row_start[n] = etot;
}

// csr[j] = src only (4B). Plain store (nt hint was a regression: no L2 merge).
__global__ void k_scatter(const int* __restrict__ srcA, const int* __restrict__ dstA,
                          const int* __restrict__ row_start, int* __restrict__ cursor,
                          int* __restrict__ csr, int e) {
    int i = blockIdx.x * 256 + threadIdx.x;
    if (i >= e) return;
    int d = dstA[i];
    int s = srcA[i];
    int p = atomicAdd(&cursor[d], 1);
    csr[row_start[d] + p] = s;
}

// ---------------- input prescale: x4[i] = dis_i * x_i (padded to float4) ----
__global__ void k_prep_x(const float* __restrict__ x, const float* __restrict__ dis,
                         float4* __restrict__ x4, int n) {
    int i = blockIdx.x * 256 + threadIdx.x;
    if (i >= n) return;
    float d = dis[i];
    x4[i] = make_float4(x[i * 3 + 0] * d, x[i * 3 + 1] * d, x[i * 3 + 2] * d, 0.f);
}

// ---------------- W prep: transpose + hi/lo fp16 split ----------------
__global__ void k_prep_wt(const float* __restrict__ Wp, __half* __restrict__ WTh,
                          __half* __restrict__ WTl, int total) {
    int t = blockIdx.x * 256 + threadIdx.x;
    if (t >= total) return;
    int l = t >> 14;
    int kc = t & 16383;
    int k = kc >> 7, c = kc & 127;
    float w = Wp[t];
    __half hi = __float2half_rn(w);
    __half lo = __float2half_rn(w - __half2float(hi));
    size_t o = ((size_t)l << 14) + (size_t)c * HW + k;
    WTh[o] = hi;
    WTl[o] = lo;
}

// ---------------- encoder ----------------
__global__ void k_enc_agg(const float4* __restrict__ x4, const int* __restrict__ rs,
                          const int* __restrict__ csr, const float* __restrict__ dis,
                          float4* __restrict__ zx, int n) {
    int i = blockIdx.x * 256 + threadIdx.x;
    if (i >= n) return;
    float4 a = x4[i];
    int e1 = rs[i + 1];
    for (int j = rs[i]; j < e1; ++j) {
        float4 v = x4[csr[j]];
        a.x += v.x; a.y += v.y; a.z += v.z;
    }
    float d = dis[i];
    zx[i] = make_float4(a.x * d, a.y * d, a.z * d, 0.f);
}

__global__ void k_enc_gemm(const float4* __restrict__ zx, const float* __restrict__ We,
                           const float* __restrict__ be, const float* __restrict__ dis,
                           __half* __restrict__ H, int n) {
    int t = blockIdx.x * 256 + threadIdx.x;
    int i = t >> 7;
    int c = t & 127;
    if (i >= n) return;
    float4 z = zx[i];
    float v = z.x * We[c] + z.y * We[HW + c] + z.z * We[2 * HW + c] + be[c];
    H[(size_t)i * HW + c] = __float2half_rn(fmaxf(v, 0.f) * dis[i]);
}

// ---------------- width-128 aggregate: 4 nodes/wave, 16 lanes/node ----------
// Lane covers 8 features (16B). One gather instruction = 4 rows = 1KB.
// Z[i] = fp16( dis_i * ( H'[i] + sum_src H'[src] ) )
__global__ __launch_bounds__(256) void k_agg128(const __half* __restrict__ Hin,
                                                const int* __restrict__ rs,
                                                const int* __restrict__ csr,
                                                const float* __restrict__ dis,
                                                __half* __restrict__ Z, int n) {
    int wave = threadIdx.x >> 6, lane = threadIdx.x & 63;
    int lg = lane & 15;  // lane in 16-lane group
    int node = (blockIdx.x * 4 + wave) * 4 + (lane >> 4);
    bool active = node < n;

    float a0[8], a1[8], a2[8], a3[8];
#pragma unroll
    for (int j = 0; j < 8; ++j) { a0[j] = 0.f; a1[j] = 0.f; a2[j] = 0.f; a3[j] = 0.f; }

    int e0 = 0, e1 = 0;
    if (active) {
        e0 = rs[node];
        e1 = rs[node + 1];
        f16x8 hv = *(const f16x8*)(Hin + (size_t)node * HW + lg * 8);
#pragma unroll
        for (int j = 0; j < 8; ++j) a0[j] = (float)hv[j];
    }

    for (int base = e0; base < e1; base += 16) {
        int cnt = e1 - base;
        if (cnt > 16) cnt = 16;
        int sl = (base + lg < e1) ? csr[base + lg] : 0;
        int k = 0;
        for (; k + 4 <= cnt; k += 4) {
            int s0 = __shfl(sl, k + 0, 16);
            int s1 = __shfl(sl, k + 1, 16);
            int s2 = __shfl(sl, k + 2, 16);
            int s3 = __shfl(sl, k + 3, 16);
            f16x8 v0 = *(const f16x8*)(Hin + (size_t)s0 * HW + lg * 8);
            f16x8 v1 = *(const f16x8*)(Hin + (size_t)s1 * HW + lg * 8);
            f16x8 v2 = *(const f16x8*)(Hin + (size_t)s2 * HW + lg * 8);
            f16x8 v3 = *(const f16x8*)(Hin + (size_t)s3 * HW + lg * 8);
#pragma unroll
            for (int j = 0; j < 8; ++j) {
                a0[j] += (float)v0[j];
                a1[j] += (float)v1[j];
                a2[j] += (float)v2[j];
                a3[j] += (float)v3[j];
            }
        }
        for (; k < cnt; ++k) {
            int s = __shfl(sl, k, 16);
            f16x8 v = *(const f16x8*)(Hin + (size_t)s * HW + lg * 8);
#pragma unroll
            for (int j = 0; j < 8; ++j) a0[j] += (float)v[j];
        }
    }

    if (active) {
        float d = dis[node];
        union { uint4 u; __half2 h[4]; } pk;
#pragma unroll
        for (int j = 0; j < 4; ++j) {
            float lo = d * ((a0[2 * j] + a1[2 * j]) + (a2[2 * j] + a3[2 * j]));
            float hi = d * ((a0[2 * j + 1] + a1[2 * j + 1]) + (a2[2 * j + 1] + a3[2 * j + 1]));
            pk.h[j] = __floats2half2_rn(lo, hi);
        }
        *(uint4*)(Z + (size_t)node * HW + lg * 8) = pk.u;
    }
}

// ---------------- MFMA GEMM: H' = dis * relu(Z @ W + b), in place -----------
// mode 0: write fp16 H'. mode 1 (last layer): skip H, emit t[row] = H'.Wd.
// Layout (16x16x32): A row=lane&15, k=(lane>>4)*8+j ; B col=lane&15, same k;
// C/D col=lane&15, row=(lane>>4)*4+reg.
#define GBM 256
__global__ __launch_bounds__(256) void k_gemm_mfma(const __half* __restrict__ Z,
                                                   const __half* __restrict__ WTh,
                                                   const __half* __restrict__ WTl,
                                                   const float* __restrict__ b,
                                                   const float* __restrict__ dis,
                                                   __half* __restrict__ Hout,
                                                   const float* __restrict__ Wd,
                                                   float* __restrict__ tout,
                                                   int mode, int n) {
    int wave = threadIdx.x >> 6, lane = threadIdx.x & 63;
    int q = lane >> 4, r16 = lane & 15;
    int row0 = blockIdx.x * GBM + wave * 64;

    f32x4 acc[4][8];
#pragma unroll
    for (int mt = 0; mt < 4; ++mt)
#pragma unroll
        for (int nt = 0; nt < 8; ++nt) acc[mt][nt] = (f32x4)0.f;

#pragma unroll
    for (int ks = 0; ks < 4; ++ks) {
        f16x8 afr[4];
#pragma unroll
        for (int mt = 0; mt < 4; ++mt) {
            int row = row0 + mt * 16 + r16;
            row = row < n ? row : (n - 1);  // clamp; results discarded at store
            afr[mt] = *(const f16x8*)(Z + (size_t)row * HW + ks * 32 + q * 8);
        }
#pragma unroll
        for (int nt = 0; nt < 8; ++nt) {
            f16x8 bh = *(const f16x8*)(WTh + (size_t)(nt * 16 + r16) * HW + ks * 32 + q * 8);
            f16x8 bl = *(const f16x8*)(WTl + (size_t)(nt * 16 + r16) * HW + ks * 32 + q * 8);
#pragma unroll
            for (int mt = 0; mt < 4; ++mt) {
                acc[mt][nt] = __builtin_amdgcn_mfma_f32_16x16x32_f16(afr[mt], bh, acc[mt][nt], 0, 0, 0);
                acc[mt][nt] = __builtin_amdgcn_mfma_f32_16x16x32_f16(afr[mt], bl, acc[mt][nt], 0, 0, 0);
            }
        }
    }

    float dr[4][4];
#pragma unroll
    for (int mt = 0; mt < 4; ++mt)
#pragma unroll
        for (int r = 0; r < 4; ++r) {
            int row = row0 + mt * 16 + q * 4 + r;
            dr[mt][r] = (row < n) ? dis[row] : 0.f;
        }
    float bias[8];
#pragma unroll
    for (int nt = 0; nt < 8; ++nt) bias[nt] = b[nt * 16 + r16];

    if (mode == 0) {
#pragma unroll
        for (int nt = 0; nt < 8; ++nt) {
#pragma unroll
            for (int mt = 0; mt < 4; ++mt) {
#pragma unroll
                for (int r = 0; r < 4; ++r) {
                    int row = row0 + mt * 16 + q * 4 + r;
                    if (row < n) {
                        float v = fmaxf(acc[mt][nt][r] + bias[nt], 0.f) * dr[mt][r];
                        Hout[(size_t)row * HW + nt * 16 + r16] = __float2half_rn(v);
                    }
                }
            }
        }
    } else {
        float wd[8];
#pragma unroll
        for (int nt = 0; nt < 8; ++nt) wd[nt] = Wd[nt * 16 + r16];
#pragma unroll
        for (int mt = 0; mt < 4; ++mt) {
#pragma unroll
            for (int r = 0; r < 4; ++r) {
                float pr = 0.f;
#pragma unroll
                for (int nt = 0; nt < 8; ++nt)
                    pr += fmaxf(acc[mt][nt][r] + bias[nt], 0.f) * wd[nt];
                pr *= dr[mt][r];
#pragma unroll
                for (int off = 1; off < 16; off <<= 1) pr += __shfl_xor(pr, off, 16);
                if (r16 == 0) {
                    int row = row0 + mt * 16 + q * 4 + r;
                    if (row < n) tout[row] = pr;
                }
            }
        }
    }
}

// ---------------- decoder output ----------------
// out[i] = (dis_i * (sum_src t[src] + t[i]) + b) * mask[i]
__global__ void k_dec_out(const float* __restrict__ t, const int* __restrict__ rs,
                          const int* __restrict__ csr, const float* __restrict__ dis,
                          const float* __restrict__ bdec, const float* __restrict__ mask,
                          float* __restrict__ out, int n) {
    int i = blockIdx.x * 256 + threadIdx.x;
    if (i >= n) return;
    float acc = t[i];
    int e1 = rs[i + 1];
    for (int j = rs[i]; j < e1; ++j) acc += t[csr[j]];
    out[i] = (dis[i] * acc + bdec[0]) * mask[i];
}

// ---------------------------------------------------------------------------
static inline size_t align256(size_t x) { return (x + 255) & ~(size_t)255; }

extern "C" void kernel_launch(void* const* d_in, const int* in_sizes, int n_in,
                              void* d_out, int out_size, void* d_ws, size_t ws_size,
                              hipStream_t stream) {
    const float* x     = (const float*)d_in[0];
    const float* mask  = (const float*)d_in[1];
    const int*   ei    = (const int*)d_in[2];
    const float* W_enc = (const float*)d_in[3];
    const float* b_enc = (const float*)d_in[4];
    const float* W_p   = (const float*)d_in[5];
    const float* b_p   = (const float*)d_in[6];
    const float* W_dec = (const float*)d_in[7];
    const float* b_dec = (const float*)d_in[8];

    const int N = in_sizes[1];
    const int E = in_sizes[2] / 2;
    const int* srcA = ei;
    const int* dstA = ei + E;

    char* p = (char*)d_ws;
    size_t off = 0;
    auto carve = [&](size_t bytes) {
        void* r = p + off;
        off += align256(bytes);
        return r;
    };
    int*    deg       = (int*)carve((size_t)N * 4);
    int*    cursor    = (int*)carve((size_t)N * 4);
    int*    row_start = (int*)carve((size_t)(N + 1) * 4);
    int*    bsum      = (int*)carve(512 * 4);
    int*    csr       = (int*)carve((size_t)E * 4);
    float*  dis       = (float*)carve((size_t)N * 4);
    float4* x4        = (float4*)carve((size_t)N * 16);
    float4* zx        = (float4*)carve((size_t)N * 16);  // also scan tmp
    float*  tdec      = (float*)carve((size_t)N * 4);
    __half* WTh       = (__half*)carve((size_t)4 * HW * HW * 2);
    __half* WTl       = (__half*)carve((size_t)4 * HW * HW * 2);
    __half* HA        = (__half*)carve((size_t)N * HW * 2);
    __half* HB        = (__half*)carve((size_t)N * HW * 2);
    int*    tmp       = (int*)zx;

    const int gN   = (N + 255) / 256;
    const int gE   = (E + 255) / 256;
    const int gAgg = (N + 15) / 16;
    const int gG   = (N + GBM - 1) / GBM;
    const int WPT  = 4 * HW * HW;

    // ---- CSR build + preps ----
    k_zero_i32<<<gN, 256, 0, stream>>>(deg, N);
    k_hist<<<gE, 256, 0, stream>>>(dstA, deg, E);
    k_scan_a<<<gN, 256, 0, stream>>>(deg, tmp, bsum, dis, N);
    k_scan_b<<<1, 512, 0, stream>>>(bsum, gN);
    k_scan_c<<<gN, 256, 0, stream>>>(tmp, deg, bsum, row_start, cursor, N, E);
    k_scatter<<<gE, 256, 0, stream>>>(srcA, dstA, row_start, cursor, csr, E);
    k_prep_x<<<gN, 256, 0, stream>>>(x, dis, x4, N);
    k_prep_wt<<<(WPT + 255) / 256, 256, 0, stream>>>(W_p, WTh, WTl, WPT);

    // ---- encoder ----
    k_enc_agg<<<gN, 256, 0, stream>>>(x4, row_start, csr, dis, zx, N);
    k_enc_gemm<<<(N * HW + 255) / 256, 256, 0, stream>>>(zx, W_enc, b_enc, dis, HA, N);

    // ---- 4 processor layers: agg(Hin->Hoth), gemm in place on Hoth ----
    // Last layer's gemm emits the decoder matvec t directly (mode 1).
    __half* Hin = HA;
    __half* Hoth = HB;
    for (int l = 0; l < 4; ++l) {
        k_agg128<<<gAgg, 256, 0, stream>>>(Hin, row_start, csr, dis, Hoth, N);
        int mode = (l == 3) ? 1 : 0;
        k_gemm_mfma<<<gG, 256, 0, stream>>>(Hoth, WTh + (size_t)l * HW * HW,
                                            WTl + (size_t)l * HW * HW,
                                            b_p + (size_t)l * HW, dis, Hoth,
                                            W_dec, tdec, mode, N);
        __half* t = Hin; Hin = Hoth; Hoth = t;
    }

    // ---- decoder output ----
    k_dec_out<<<gN, 256, 0, stream>>>(tdec, row_start, csr, dis, b_dec, mask,
                                      (float*)d_out, N);
}